// Round 1
// baseline (1092.831 us; speedup 1.0000x reference)
//
#include <hip/hip_runtime.h>
#include <math.h>

#define HID 64
#define HEADS 4
#define LAYERS 4
#define NRBF 20
#define NG 256
#define CB 512     // HID*8 floats per node (channels x blades)
#define CAP 128    // edge chunk per block in aggregation
#define NPB 8      // nodes per block in projection

__device__ __forceinline__ int gradeOf(int b){ return (b==0)?0:((b<4)?1:((b<7)?2:3)); }

// ---------- prep: transpose weights into coalescing-friendly layouts ----------
__global__ void prep_kernel(const float* __restrict__ proj_w, const float* __restrict__ inproj_w,
                            const float* __restrict__ prepool_w, const float* __restrict__ post_w1,
                            float* __restrict__ W2, float* __restrict__ inwT,
                            float* __restrict__ ppw0T, float* __restrict__ w1T){
    int idx = blockIdx.x*256 + threadIdx.x;
    const int szW2 = LAYERS*HID*CB;          // 131072
    if (idx < szW2){
        int l = idx/(HID*CB); int r = idx%(HID*CB); int i = r/CB; int t = r%CB;
        int o = t>>3, b = t&7; int g = gradeOf(b);
        W2[idx] = proj_w[(((size_t)l*4+g)*HID + o)*HID + i];
    } else if (idx < szW2 + 65*HID){
        int r = idx - szW2; int i = r/HID, o = r%HID;
        inwT[r] = inproj_w[o*65 + i];
    } else if (idx < szW2 + 65*HID + HID*HID){
        int r = idx - szW2 - 65*HID; int i = r/HID, o = r%HID;
        ppw0T[r] = prepool_w[o*HID + i];          // grade-0 block of (4,64,64)
    } else if (idx < szW2 + 65*HID + 2*HID*HID){
        int r = idx - szW2 - 65*HID - HID*HID; int i = r/HID, o = r%HID;
        w1T[r] = post_w1[o*HID + i];
    }
}

// ---------- per-graph position sums for centering ----------
__global__ void node_stats_kernel(const float* __restrict__ pos, const int* __restrict__ batch,
                                  float* possum, float* pcnt, int N){
    int n = blockIdx.x*256 + threadIdx.x; if (n>=N) return;
    int g = batch[n];
    atomicAdd(&possum[g*3+0], pos[n*3+0]);
    atomicAdd(&possum[g*3+1], pos[n*3+1]);
    atomicAdd(&possum[g*3+2], pos[n*3+2]);
    atomicAdd(&pcnt[g], 1.0f);
}

// ---------- edge MLP: dist -> RBF(20) -> 64 (silu) -> 4, plus dst-degree count ----------
__global__ void edge_kernel(const float* __restrict__ pos, const int* __restrict__ ei, int E,
                            const float* __restrict__ ew1, const float* __restrict__ eb1,
                            const float* __restrict__ ew2, const float* __restrict__ eb2,
                            float* __restrict__ edge_scalar, int* counts){
    __shared__ float w1[HID*NRBF], b1[HID], w2[HEADS*HID], b2s[HEADS];
    for (int i=threadIdx.x;i<HID*NRBF;i+=blockDim.x) w1[i]=ew1[i];
    for (int i=threadIdx.x;i<HID;i+=blockDim.x) b1[i]=eb1[i];
    for (int i=threadIdx.x;i<HEADS*HID;i+=blockDim.x) w2[i]=ew2[i];
    if (threadIdx.x<HEADS) b2s[threadIdx.x]=eb2[threadIdx.x];
    __syncthreads();
    int e = blockIdx.x*blockDim.x + threadIdx.x; if (e>=E) return;
    int s = ei[e], d = ei[E+e];
    float dx = pos[s*3+0]-pos[d*3+0];
    float dy = pos[s*3+1]-pos[d*3+1];
    float dz = pos[s*3+2]-pos[d*3+2];
    float dist = sqrtf(dx*dx+dy*dy+dz*dz);
    float t0 = dist * (19.0f/10.0f);     // (dist - k*w)/w = dist/w - k, w = 10/19
    float rbf[NRBF];
    #pragma unroll
    for (int k=0;k<NRBF;k++){ float a = t0 - (float)k; rbf[k]=__expf(-0.5f*a*a); }
    float acc0=b2s[0], acc1=b2s[1], acc2=b2s[2], acc3=b2s[3];
    for (int o=0;o<HID;o++){
        float hv = b1[o];
        #pragma unroll
        for (int k=0;k<NRBF;k++) hv += rbf[k]*w1[o*NRBF+k];
        float act = hv * (1.0f/(1.0f+__expf(-hv)));
        acc0 += act*w2[0*HID+o]; acc1 += act*w2[1*HID+o];
        acc2 += act*w2[2*HID+o]; acc3 += act*w2[3*HID+o];
    }
    edge_scalar[e*4+0]=acc0; edge_scalar[e*4+1]=acc1;
    edge_scalar[e*4+2]=acc2; edge_scalar[e*4+3]=acc3;
    atomicAdd(&counts[d],1);
}

// ---------- single-block exclusive scan of dst counts -> CSR indptr + cursor; also pos means ----------
__global__ void scan_kernel(const int* __restrict__ counts, int* indptr, int* cursor, int N,
                            const float* __restrict__ possum, const float* __restrict__ pcnt,
                            float* pmean){
    __shared__ int sc[1024];
    __shared__ int carry_s;
    int t = threadIdx.x;
    if (t==0) carry_s = 0;
    __syncthreads();
    for (int base=0; base<N; base+=1024){
        int v = (base+t<N)? counts[base+t] : 0;
        sc[t]=v; __syncthreads();
        for (int off=1; off<1024; off<<=1){
            int add = (t>=off)? sc[t-off] : 0;
            __syncthreads();
            sc[t]+=add; __syncthreads();
        }
        int incl = sc[t];
        int carry = carry_s;
        if (base+t<N){ int ex = carry+incl-v; indptr[base+t]=ex; cursor[base+t]=ex; }
        __syncthreads();
        if (t==1023) carry_s = carry + incl;
        __syncthreads();
    }
    if (t==0) indptr[N]=carry_s;
    for (int i=t;i<NG;i+=1024){
        float c = pcnt[i]; float cm = c>1.0f?c:1.0f;
        pmean[i*3+0]=possum[i*3+0]/cm;
        pmean[i*3+1]=possum[i*3+1]/cm;
        pmean[i*3+2]=possum[i*3+2]/cm;
    }
}

__global__ void fill_kernel(const int* __restrict__ ei, int E, int* cursor, int* eids){
    int e = blockIdx.x*blockDim.x + threadIdx.x; if (e>=E) return;
    int d = ei[E+e];
    int p = atomicAdd(&cursor[d],1);
    eids[p]=e;
}

// ---------- initial node embedding ----------
__global__ void embed_kernel(const float* __restrict__ atom_w, const int* __restrict__ zidx,
                             const float* __restrict__ inwT, const float* __restrict__ inb,
                             const float* __restrict__ pos, const float* __restrict__ pmean,
                             const int* __restrict__ batch, float* __restrict__ h, int N){
    int n = blockIdx.x; int o = threadIdx.x;     // 64 threads
    __shared__ float emb[HID];
    emb[o] = atom_w[zidx[n]*HID + o];
    __syncthreads();
    float acc = inb[o];
    for (int i=0;i<HID;i++) acc += emb[i]*inwT[i*HID+o];
    int g = batch[n];
    float px = pos[n*3+0]-pmean[g*3+0];
    float py = pos[n*3+1]-pmean[g*3+1];
    float pz = pos[n*3+2]-pmean[g*3+2];
    float wv = inwT[HID*HID + o];                // inproj_w[o][64]
    float4* hp = (float4*)&h[(size_t)n*CB + o*8];
    hp[0] = make_float4(acc, wv*px, wv*py, wv*pz);
    hp[1] = make_float4(0.f,0.f,0.f,0.f);
}

// ---------- per-blade (per-grade weight) projection: z = MVLinear(h), 8 nodes/block ----------
__global__ __launch_bounds__(512) void proj_kernel(const float* __restrict__ h, const float* __restrict__ W2l,
                            const float* __restrict__ pbl, float* __restrict__ z, int N){
    __shared__ float xl[NPB][CB];
    int t = threadIdx.x; int b = t&7; int o = t>>3;
    int n0 = blockIdx.x*NPB;
    for (int nn=0;nn<NPB;nn++){
        int n = n0+nn;
        xl[nn][t] = (n<N)? h[(size_t)n*CB + t] : 0.0f;
    }
    __syncthreads();
    float acc[NPB];
    #pragma unroll
    for (int nn=0;nn<NPB;nn++) acc[nn]=0.f;
    for (int i=0;i<HID;i++){
        float w = W2l[i*CB + t];                 // coalesced, L2-resident
        #pragma unroll
        for (int nn=0;nn<NPB;nn++) acc[nn] += w * xl[nn][i*8+b];  // LDS broadcast
    }
    float bias = (b==0)? pbl[o] : 0.0f;
    for (int nn=0;nn<NPB;nn++){
        int n = n0+nn; if (n<N) z[(size_t)n*CB + t] = acc[nn] + bias;
    }
}

// ---------- per-node attention logits s_src/s_dst (one wave per node) ----------
__global__ void s_kernel(const float* __restrict__ z, const float* __restrict__ a_src_l,
                         const float* __restrict__ a_dst_l, const float* __restrict__ w_src_l,
                         const float* __restrict__ w_dst_l, float* s_src, float* s_dst, int N){
    int wave = (blockIdx.x*blockDim.x + threadIdx.x)>>6;
    int lane = threadIdx.x & 63;
    if (wave >= N) return;
    int n = wave;
    const float4* zp = (const float4*)&z[(size_t)n*CB + lane*8];
    float4 z0 = zp[0], z1 = zp[1];
    float zz[8] = {z0.x,z0.y,z0.z,z0.w,z1.x,z1.y,z1.z,z1.w};
    int head = lane>>4;
    float ps=0.f, pd=0.f;
    #pragma unroll
    for (int k=0;k<8;k++){
        int g = gradeOf(k);
        float as = a_src_l[lane*8+k]*w_src_l[head*4+g];
        float ad = a_dst_l[lane*8+k]*w_dst_l[head*4+g];
        ps += zz[k]*as; pd += zz[k]*ad;
    }
    #pragma unroll
    for (int off=1; off<16; off<<=1){
        ps += __shfl_xor(ps, off, 64);
        pd += __shfl_xor(pd, off, 64);
    }
    if ((lane&15)==0){ s_src[n*4+head]=ps; s_dst[n*4+head]=pd; }
}

// ---------- fused: softmax attention aggregate + mvSiLU + residual + mvLayerNorm ----------
__global__ __launch_bounds__(512) void agg_kernel(const float* __restrict__ z, const float* __restrict__ s_src,
                           const float* __restrict__ s_dst, const float* __restrict__ edge_scalar,
                           const int* __restrict__ eids, const int* __restrict__ indptr,
                           const int* __restrict__ ei, int E,
                           const float* __restrict__ silu_a_l, const float* __restrict__ silu_b_l,
                           const float* __restrict__ ln_a_l, float* __restrict__ h, int N){
    int n = blockIdx.x; int t = threadIdx.x;
    int b = t&7, c = t>>3, head = t>>7;
    int wv = t>>6, lane = t&63;
    __shared__ float sdl[4];
    __shared__ float mred[8][4];
    __shared__ float mfin[4];
    __shared__ int   le[CAP];
    __shared__ float lw[CAP*4];
    __shared__ float xs[CB];
    __shared__ float ncs[HID];
    __shared__ float mean_s;
    int beg = indptr[n], end = indptr[n+1];
    if (t<4) sdl[t] = s_dst[n*4+t];
    __syncthreads();
    // pass 1: per-head max of leaky_relu logits
    float m0=-1e30f,m1=-1e30f,m2=-1e30f,m3=-1e30f;
    for (int idx=beg+t; idx<end; idx+=512){
        int e = eids[idx]; int s = ei[e];
        float e0 = s_src[s*4+0]+sdl[0]+edge_scalar[e*4+0]; e0 = (e0>=0.f)?e0:0.2f*e0;
        float e1 = s_src[s*4+1]+sdl[1]+edge_scalar[e*4+1]; e1 = (e1>=0.f)?e1:0.2f*e1;
        float e2 = s_src[s*4+2]+sdl[2]+edge_scalar[e*4+2]; e2 = (e2>=0.f)?e2:0.2f*e2;
        float e3 = s_src[s*4+3]+sdl[3]+edge_scalar[e*4+3]; e3 = (e3>=0.f)?e3:0.2f*e3;
        m0=fmaxf(m0,e0); m1=fmaxf(m1,e1); m2=fmaxf(m2,e2); m3=fmaxf(m3,e3);
    }
    #pragma unroll
    for (int off=1; off<64; off<<=1){
        m0=fmaxf(m0,__shfl_xor(m0,off,64)); m1=fmaxf(m1,__shfl_xor(m1,off,64));
        m2=fmaxf(m2,__shfl_xor(m2,off,64)); m3=fmaxf(m3,__shfl_xor(m3,off,64));
    }
    if (lane==0){ mred[wv][0]=m0; mred[wv][1]=m1; mred[wv][2]=m2; mred[wv][3]=m3; }
    __syncthreads();
    if (t<4){
        float mm=-1e30f;
        for (int w=0;w<8;w++) mm=fmaxf(mm,mred[w][t]);
        mfin[t]=mm;
    }
    __syncthreads();
    // pass 2: fused numerator + denominator (normalization is linear)
    float acc=0.f, dn=0.f;
    for (int base=beg; base<end; base+=CAP){
        int cnt = min(CAP, end-base);
        if (t<cnt){
            int e = eids[base+t]; int s = ei[e];
            #pragma unroll
            for (int hh=0; hh<4; hh++){
                float ev = s_src[s*4+hh]+sdl[hh]+edge_scalar[e*4+hh];
                ev = (ev>=0.f)?ev:0.2f*ev;
                lw[t*4+hh] = __expf(ev - mfin[hh]);
            }
            le[t] = s*CB;
        }
        __syncthreads();
        for (int j=0;j<cnt;j++){
            float wj = lw[j*4+head];
            acc += wj * z[(size_t)le[j] + t];     // coalesced 2KB row gather
            dn  += wj;
        }
        __syncthreads();
    }
    float x = acc/(dn + 1e-16f);
    xs[t] = x; __syncthreads();
    // mvSiLU on attention output
    int g = gradeOf(b);
    int cb = c*8;
    float norm;
    if (g==0)      norm = xs[cb];
    else if (g==1) norm = xs[cb+1]*xs[cb+1]+xs[cb+2]*xs[cb+2]+xs[cb+3]*xs[cb+3];
    else if (g==2) norm = xs[cb+4]*xs[cb+4]+xs[cb+5]*xs[cb+5]+xs[cb+6]*xs[cb+6];
    else           norm = xs[cb+7]*xs[cb+7];
    float gate = 1.0f/(1.0f+__expf(-(silu_a_l[c*4+g]*norm + silu_b_l[c*4+g])));
    float val = gate*x + h[(size_t)n*CB + t];     // + residual
    __syncthreads();
    xs[t] = val; __syncthreads();
    // mvLayerNorm
    if (b==0){
        float ss=0.f;
        #pragma unroll
        for (int k=0;k<8;k++){ float v = xs[cb+k]; ss += v*v; }
        ncs[c] = sqrtf(ss);
    }
    __syncthreads();
    if (wv==0){
        float v = ncs[lane];
        #pragma unroll
        for (int off=1; off<64; off<<=1) v += __shfl_xor(v,off,64);
        if (lane==0) mean_s = v*(1.0f/64.0f) + 1e-6f;
    }
    __syncthreads();
    h[(size_t)n*CB + t] = ln_a_l[c]*val/mean_s;
}

// ---------- prepool (scalar blade) + graph readout sum ----------
__global__ void prepool_kernel(const float* __restrict__ h, const float* __restrict__ ppw0T,
                               const float* __restrict__ ppb, const int* __restrict__ batch,
                               float* g, int N){
    int n = blockIdx.x; int o = threadIdx.x;  // 64 threads
    __shared__ float xs[HID];
    xs[o] = h[(size_t)n*CB + o*8];            // blade 0 of channel o
    __syncthreads();
    float acc = ppb[o];
    for (int i=0;i<HID;i++) acc += xs[i]*ppw0T[i*HID+o];
    atomicAdd(&g[batch[n]*HID + o], acc);
}

__global__ void final_kernel(const float* __restrict__ g, const float* __restrict__ w1T,
                             const float* __restrict__ b1, const float* __restrict__ w2,
                             const float* __restrict__ b2, float* out){
    int gid = blockIdx.x; int o = threadIdx.x;  // 64 threads = 1 wave
    __shared__ float gl[HID];
    gl[o] = g[gid*HID + o]; __syncthreads();
    float a = b1[o];
    for (int i=0;i<HID;i++) a += gl[i]*w1T[i*HID+o];
    float act = a/(1.0f+__expf(-a));
    float p = act * w2[o];
    #pragma unroll
    for (int off=1; off<64; off<<=1) p += __shfl_xor(p,off,64);
    if (o==0) out[gid] = p + b2[0];
}

extern "C" void kernel_launch(void* const* d_in, const int* in_sizes, int n_in,
                              void* d_out, int out_size, void* d_ws, size_t ws_size,
                              hipStream_t stream) {
    const float* pos      = (const float*)d_in[0];
    const int*   zidx     = (const int*)  d_in[1];
    const int*   ei       = (const int*)  d_in[2];
    const int*   batch    = (const int*)  d_in[3];
    const float* atom_w   = (const float*)d_in[4];
    const float* inproj_w = (const float*)d_in[5];
    const float* inproj_b = (const float*)d_in[6];
    const float* edge_w1  = (const float*)d_in[7];
    const float* edge_b1  = (const float*)d_in[8];
    const float* edge_w2  = (const float*)d_in[9];
    const float* edge_b2  = (const float*)d_in[10];
    const float* proj_w   = (const float*)d_in[11];
    const float* proj_b   = (const float*)d_in[12];
    const float* a_src    = (const float*)d_in[13];
    const float* a_dst    = (const float*)d_in[14];
    const float* w_src    = (const float*)d_in[15];
    const float* w_dst    = (const float*)d_in[16];
    const float* ln_a     = (const float*)d_in[17];
    const float* silu_a   = (const float*)d_in[18];
    const float* silu_b   = (const float*)d_in[19];
    const float* prepool_w= (const float*)d_in[20];
    const float* prepool_b= (const float*)d_in[21];
    const float* post_w1  = (const float*)d_in[22];
    const float* post_b1  = (const float*)d_in[23];
    const float* post_w2  = (const float*)d_in[24];
    const float* post_b2  = (const float*)d_in[25];
    float* out = (float*)d_out;

    const int N = in_sizes[0]/3;
    const int E = in_sizes[2]/2;

    // ---- workspace layout (4B units, 64-element aligned) ----
    float* wsf = (float*)d_ws;
    size_t off = 0;
    auto alloc = [&](size_t nelem){ size_t r = off; off += (nelem + 63) & ~(size_t)63; return r; };
    size_t o_counts = alloc(N);          // int
    size_t o_possum = alloc(NG*3);
    size_t o_pcnt   = alloc(NG);
    size_t o_g      = alloc(NG*HID);
    size_t zero_end = off;               // everything above must start at 0
    size_t o_indptr = alloc(N+1);        // int
    size_t o_cursor = alloc(N);          // int
    size_t o_eids   = alloc(E);          // int
    size_t o_pmean  = alloc(NG*3);
    size_t o_esc    = alloc((size_t)E*4);
    size_t o_ssrc   = alloc((size_t)N*4);
    size_t o_sdst   = alloc((size_t)N*4);
    size_t o_inwT   = alloc(65*HID);
    size_t o_W2     = alloc((size_t)LAYERS*HID*CB);
    size_t o_ppw0T  = alloc(HID*HID);
    size_t o_w1T    = alloc(HID*HID);
    size_t o_h      = alloc((size_t)N*CB);
    size_t o_z      = alloc((size_t)N*CB);

    int*   counts = (int*)(wsf + o_counts);
    float* possum = wsf + o_possum;
    float* pcnt   = wsf + o_pcnt;
    float* gbuf   = wsf + o_g;
    int*   indptr = (int*)(wsf + o_indptr);
    int*   cursor = (int*)(wsf + o_cursor);
    int*   eids   = (int*)(wsf + o_eids);
    float* pmean  = wsf + o_pmean;
    float* esc    = wsf + o_esc;
    float* ssrc   = wsf + o_ssrc;
    float* sdst   = wsf + o_sdst;
    float* inwT   = wsf + o_inwT;
    float* W2     = wsf + o_W2;
    float* ppw0T  = wsf + o_ppw0T;
    float* w1T    = wsf + o_w1T;
    float* hbuf   = wsf + o_h;
    float* zbuf   = wsf + o_z;

    // zero the accumulators (ws is poisoned 0xAA before every call)
    hipMemsetAsync(wsf, 0, zero_end*sizeof(float), stream);

    // weight transposes
    {
        int total = LAYERS*HID*CB + 65*HID + 2*HID*HID;
        prep_kernel<<<(total+255)/256, 256, 0, stream>>>(proj_w, inproj_w, prepool_w, post_w1,
                                                         W2, inwT, ppw0T, w1T);
    }
    node_stats_kernel<<<(N+255)/256, 256, 0, stream>>>(pos, batch, possum, pcnt, N);
    edge_kernel<<<(E+255)/256, 256, 0, stream>>>(pos, ei, E, edge_w1, edge_b1, edge_w2, edge_b2,
                                                 esc, counts);
    scan_kernel<<<1, 1024, 0, stream>>>(counts, indptr, cursor, N, possum, pcnt, pmean);
    fill_kernel<<<(E+255)/256, 256, 0, stream>>>(ei, E, cursor, eids);
    embed_kernel<<<N, HID, 0, stream>>>(atom_w, zidx, inwT, inproj_b, pos, pmean, batch, hbuf, N);

    for (int l=0; l<LAYERS; l++){
        proj_kernel<<<(N+NPB-1)/NPB, 512, 0, stream>>>(hbuf, W2 + (size_t)l*HID*CB,
                                                       proj_b + l*HID, zbuf, N);
        s_kernel<<<(N*64+255)/256, 256, 0, stream>>>(zbuf, a_src + l*512, a_dst + l*512,
                                                     w_src + l*16, w_dst + l*16, ssrc, sdst, N);
        agg_kernel<<<N, 512, 0, stream>>>(zbuf, ssrc, sdst, esc, eids, indptr, ei, E,
                                          silu_a + l*HID*4, silu_b + l*HID*4,
                                          ln_a + l*HID, hbuf, N);
    }

    prepool_kernel<<<N, HID, 0, stream>>>(hbuf, ppw0T, prepool_b, batch, gbuf, N);
    final_kernel<<<NG, HID, 0, stream>>>(gbuf, w1T, post_b1, post_w2, post_b2, out);
}